// Round 12
// baseline (2669.542 us; speedup 1.0000x reference)
//
#include <hip/hip_runtime.h>

#define NN 100000
#define D 128
#define D2 256
#define NB 1563                     // ceil(NN/64) buckets of 64 nodes
#define SCAN_T 1024
#define SCAN_CH ((NN + SCAN_T - 1) / SCAN_T)   // 98

typedef unsigned short u16;
typedef unsigned int u32;
typedef __attribute__((ext_vector_type(8))) short short8v;
typedef __attribute__((ext_vector_type(8))) unsigned short ushort8v;
typedef __attribute__((ext_vector_type(16))) float f32x16;

__device__ __forceinline__ u16 f2bf(float f) {
  union { float f; u32 u; } v; v.f = f;
  u32 r = v.u + 0x7fffu + ((v.u >> 16) & 1u);   // round-nearest-even
  return (u16)(r >> 16);
}
__device__ __forceinline__ float bf2f(u16 u) {
  union { u32 u; float f; } v; v.u = ((u32)u) << 16;
  return v.f;
}
__device__ __forceinline__ void fma4(float4& acc, float a, const float4& w) {
  acc.x = fmaf(a, w.x, acc.x);
  acc.y = fmaf(a, w.y, acc.y);
  acc.z = fmaf(a, w.z, acc.z);
  acc.w = fmaf(a, w.w, acc.w);
}

// ---------- binned aggregation path ----------
// B1: global per-bucket histogram (LDS-aggregated; 256*NB global atomics total)
__global__ __launch_bounds__(256) void k_hist(const int* __restrict__ dsts,
                                              int* __restrict__ gh, int E) {
  __shared__ int lh[NB];
  for (int i = threadIdx.x; i < NB; i += 256) lh[i] = 0;
  __syncthreads();
  for (int j = blockIdx.x * 256 + threadIdx.x; j < E; j += gridDim.x * 256)
    atomicAdd(&lh[dsts[j] >> 6], 1);
  __syncthreads();
  for (int i = threadIdx.x; i < NB; i += 256)
    if (lh[i]) atomicAdd(&gh[i], lh[i]);
}

// B2: exclusive scan over NB bucket counts (1 block, 2 elems/thread)
__global__ __launch_bounds__(1024) void k_binscan(const int* __restrict__ gh,
    int* __restrict__ gofs, int* __restrict__ gcur) {
  __shared__ int part[1024];
  const int t = threadIdx.x;
  const int i0 = 2 * t, i1 = 2 * t + 1;
  const int a = (i0 < NB) ? gh[i0] : 0;
  const int b = (i1 < NB) ? gh[i1] : 0;
  part[t] = a + b;
  __syncthreads();
  for (int off = 1; off < 1024; off <<= 1) {
    const int v = (t >= off) ? part[t - off] : 0;
    __syncthreads();
    part[t] += v;
    __syncthreads();
  }
  const int base = t ? part[t - 1] : 0;
  if (i0 < NB) { gofs[i0] = base; gcur[i0] = base; }
  if (i1 < NB) { gofs[i1] = base + a; gcur[i1] = base + a; }
  if (t == 0) gofs[NB] = part[1023];
}

// B3: bin edges into bucket-grouped pairs (src<<6 | dst&63).
// One global cursor atomic per (block,bucket); pair writes contiguous per run.
__global__ __launch_bounds__(256) void k_bin(const int* __restrict__ srcs,
    const int* __restrict__ dsts, int* __restrict__ gcur,
    u32* __restrict__ pairs, int E) {
  __shared__ int lh[NB], lbase[NB];
  const int chunk = (E + gridDim.x - 1) / gridDim.x;
  const int beg = blockIdx.x * chunk;
  const int end = min(beg + chunk, E);
  for (int i = threadIdx.x; i < NB; i += 256) lh[i] = 0;
  __syncthreads();
  for (int j = beg + threadIdx.x; j < end; j += 256)
    atomicAdd(&lh[dsts[j] >> 6], 1);
  __syncthreads();
  for (int i = threadIdx.x; i < NB; i += 256) {
    const int c = lh[i];
    lbase[i] = c ? atomicAdd(&gcur[i], c) : 0;
    lh[i] = 0;
  }
  __syncthreads();
  for (int j = beg + threadIdx.x; j < end; j += 256) {
    const int d = dsts[j];
    const int s = srcs[j];
    const int bb = d >> 6;
    const int loc = atomicAdd(&lh[bb], 1);
    pairs[lbase[bb] + loc] = ((u32)s << 6) | (u32)(d & 63);
  }
}

// B4: per-bucket LDS f32 accumulation + self-term + bf16 writeout.
// One WG per bucket (64 nodes x 128 cols slice = 32 KB LDS, 5 WG/CU).
__global__ __launch_bounds__(256) void k_bagg(const float* __restrict__ x,
    const float* __restrict__ epsp, const int* __restrict__ gofs,
    const u32* __restrict__ pairs, u16* __restrict__ h0bf) {
  __shared__ float slice[64 * 128];
  for (int i = threadIdx.x; i < 64 * 128; i += 256) slice[i] = 0.0f;
  __syncthreads();
  const int lane = threadIdx.x & 63;
  const int w = threadIdx.x >> 6;
  const int b = blockIdx.x;
  const float2* xx2 = (const float2*)x;
  const int beg = gofs[b], end = gofs[b + 1];
  const int len = end - beg;
  const int qb = beg + (len * w) / 4;
  const int qe = beg + (len * (w + 1)) / 4;
  int j = qb;
  for (; j + 4 <= qe; j += 4) {
    const u32 p0 = pairs[j], p1 = pairs[j + 1];
    const u32 p2 = pairs[j + 2], p3 = pairs[j + 3];
    const float2 v0 = xx2[(size_t)(p0 >> 6) * 64 + lane];
    const float2 v1 = xx2[(size_t)(p1 >> 6) * 64 + lane];
    const float2 v2 = xx2[(size_t)(p2 >> 6) * 64 + lane];
    const float2 v3 = xx2[(size_t)(p3 >> 6) * 64 + lane];
    atomicAdd(&slice[(p0 & 63) * 128 + 2 * lane], v0.x);
    atomicAdd(&slice[(p0 & 63) * 128 + 2 * lane + 1], v0.y);
    atomicAdd(&slice[(p1 & 63) * 128 + 2 * lane], v1.x);
    atomicAdd(&slice[(p1 & 63) * 128 + 2 * lane + 1], v1.y);
    atomicAdd(&slice[(p2 & 63) * 128 + 2 * lane], v2.x);
    atomicAdd(&slice[(p2 & 63) * 128 + 2 * lane + 1], v2.y);
    atomicAdd(&slice[(p3 & 63) * 128 + 2 * lane], v3.x);
    atomicAdd(&slice[(p3 & 63) * 128 + 2 * lane + 1], v3.y);
  }
  for (; j < qe; ++j) {
    const u32 p = pairs[j];
    const float2 v = xx2[(size_t)(p >> 6) * 64 + lane];
    atomicAdd(&slice[(p & 63) * 128 + 2 * lane], v.x);
    atomicAdd(&slice[(p & 63) * 128 + 2 * lane + 1], v.y);
  }
  __syncthreads();
  const float ep = 1.0f + epsp[0];
  for (int i = w * 16; i < w * 16 + 16; ++i) {
    const int n = b * 64 + i;
    if (n >= NN) break;
    const float2 xv = xx2[(size_t)n * 64 + lane];
    const float f0 = slice[i * 128 + 2 * lane] + ep * xv.x;
    const float f1 = slice[i * 128 + 2 * lane + 1] + ep * xv.y;
    const u32 pk = (u32)f2bf(f0) | ((u32)f2bf(f1) << 16);
    ((u32*)(h0bf + (size_t)n * D))[lane] = pk;
  }
}

// ---------- MFMA MLP (R11-proven) ----------
__global__ void k_wprep(const float* __restrict__ W1, const float* __restrict__ W2,
                        u16* __restrict__ w1tr, u16* __restrict__ w2tr) {
  const int t = blockIdx.x * blockDim.x + threadIdx.x;
  if (t < 32768) {
    const int n = t >> 7, k = t & 127;
    w1tr[t] = f2bf(W1[k * 256 + n]);
  } else if (t < 65536) {
    const int i = t - 32768;
    const int n = i >> 8, k = i & 255;
    w2tr[i] = f2bf(W2[k * 128 + n]);
  }
}

// h1 = h0bf @ W1tr^T + b1 (32x32x16 bf16 MFMA) with fused BN stats
__global__ __launch_bounds__(256) void k_gemm1_mfma(const u16* __restrict__ h0bf,
    const u16* __restrict__ w1tr, const float* __restrict__ b1, u16* __restrict__ h1,
    float* __restrict__ stats) {
  __shared__ float ls[512];
  if (threadIdx.x < 256) { ls[threadIdx.x] = 0.0f; ls[threadIdx.x + 256] = 0.0f; }
  __syncthreads();
  const int lane = threadIdx.x & 63;
  const int l31 = lane & 31;
  const int khalf = (lane >> 5) * 8;
  const int gw = blockIdx.x * 4 + (threadIdx.x >> 6);
  const int nwv = gridDim.x * 4;
  for (int task = gw; task < (NN / 32) * 2; task += nwv) {
    const int chunk = task >> 1, cg = task & 1;
    const int arow = chunk * 32 + l31;
    f32x16 acc[4];
    #pragma unroll
    for (int i = 0; i < 4; ++i)
      #pragma unroll
      for (int j = 0; j < 16; ++j) acc[i][j] = 0.0f;
    const u16* ap = h0bf + (size_t)arow * 128 + khalf;
    const u16* bp = w1tr + ((size_t)(cg * 128 + l31)) * 128 + khalf;
    #pragma unroll
    for (int ks = 0; ks < 8; ++ks) {
      const short8v av = *(const short8v*)(ap + ks * 16);
      #pragma unroll
      for (int i = 0; i < 4; ++i) {
        const short8v bv = *(const short8v*)(bp + (size_t)i * 32 * 128 + ks * 16);
        acc[i] = __builtin_amdgcn_mfma_f32_32x32x16_bf16(av, bv, acc[i], 0, 0, 0);
      }
    }
    const int r0 = chunk * 32 + 4 * (lane >> 5);
    #pragma unroll
    for (int i = 0; i < 4; ++i) {
      const int col = cg * 128 + i * 32 + l31;
      const float bias = b1[col];
      float psum = 0.0f, psq = 0.0f;
      #pragma unroll
      for (int g = 0; g < 4; ++g)
        #pragma unroll
        for (int j = 0; j < 4; ++j) {
          const int row = r0 + 8 * g + j;
          const float h = acc[i][g * 4 + j] + bias;
          h1[(size_t)row * 256 + col] = f2bf(h);
          psum += h;
          psq += h * h;
        }
      unsafeAtomicAdd(&ls[col], psum);
      unsafeAtomicAdd(&ls[col + 256], psq);
    }
  }
  __syncthreads();
  if (threadIdx.x < 256) {
    unsafeAtomicAdd(&stats[threadIdx.x], ls[threadIdx.x]);
    unsafeAtomicAdd(&stats[threadIdx.x + 256], ls[threadIdx.x + 256]);
  }
}

__global__ void k_finalize(const float* __restrict__ gamma, const float* __restrict__ beta,
                           float* __restrict__ stats) {
  const int j = threadIdx.x;
  const float inv = 1.0f / (float)NN;
  const float mu = stats[j] * inv;
  const float var = fmaxf(stats[D2 + j] * inv - mu * mu, 0.0f);
  const float sc = gamma[j] * rsqrtf(var + 1e-5f);
  stats[2 * D2 + j] = sc;
  stats[3 * D2 + j] = beta[j] - mu * sc;
}

__global__ __launch_bounds__(256) void k_bnrelu(u16* h1, const float* __restrict__ stats) {
  const int tid = blockIdx.x * blockDim.x + threadIdx.x;
  const int c0 = (tid * 8) & 255;
  const float4 s0 = *(const float4*)(stats + 512 + c0);
  const float4 s1 = *(const float4*)(stats + 512 + c0 + 4);
  const float4 t0 = *(const float4*)(stats + 768 + c0);
  const float4 t1 = *(const float4*)(stats + 768 + c0 + 4);
  const float sv[8] = {s0.x, s0.y, s0.z, s0.w, s1.x, s1.y, s1.z, s1.w};
  const float tv[8] = {t0.x, t0.y, t0.z, t0.w, t1.x, t1.y, t1.z, t1.w};
  const int total = NN * D2 / 8;
  for (int i = tid; i < total; i += gridDim.x * blockDim.x) {
    ushort8v v = ((const ushort8v*)h1)[i];
    #pragma unroll
    for (int j = 0; j < 8; ++j)
      v[j] = f2bf(fmaxf(fmaf(bf2f(v[j]), sv[j], tv[j]), 0.0f));
    ((ushort8v*)h1)[i] = v;
  }
}

__global__ __launch_bounds__(256) void k_gemm2_mfma(const u16* h1, float* outp,
    const u16* __restrict__ w2tr, const float* __restrict__ b2) {
  const int lane = threadIdx.x & 63;
  const int l31 = lane & 31;
  const int khalf = (lane >> 5) * 8;
  const int gw = blockIdx.x * 4 + (threadIdx.x >> 6);
  const int nwv = gridDim.x * 4;
  for (int chunk = gw; chunk < NN / 32; chunk += nwv) {
    const int arow = chunk * 32 + l31;
    f32x16 acc[4];
    #pragma unroll
    for (int i = 0; i < 4; ++i)
      #pragma unroll
      for (int j = 0; j < 16; ++j) acc[i][j] = 0.0f;
    const u16* ap = h1 + (size_t)arow * 256 + khalf;
    const u16* bp = w2tr + (size_t)l31 * 256 + khalf;
    #pragma unroll
    for (int ks = 0; ks < 16; ++ks) {
      const short8v av = *(const short8v*)(ap + ks * 16);
      #pragma unroll
      for (int i = 0; i < 4; ++i) {
        const short8v bv = *(const short8v*)(bp + (size_t)i * 32 * 256 + ks * 16);
        acc[i] = __builtin_amdgcn_mfma_f32_32x32x16_bf16(av, bv, acc[i], 0, 0, 0);
      }
    }
    const int r0 = chunk * 32 + 4 * (lane >> 5);
    #pragma unroll
    for (int i = 0; i < 4; ++i) {
      const int col = i * 32 + l31;
      const float bias = b2[col];
      #pragma unroll
      for (int g = 0; g < 4; ++g)
        #pragma unroll
        for (int j = 0; j < 4; ++j) {
          const int row = r0 + 8 * g + j;
          outp[(size_t)row * 128 + col] = acc[i][g * 4 + j] + bias;
        }
    }
  }
}

// ---------- fallback tiers (proven R6/R8) ----------
__global__ void k_count(const int* __restrict__ dsts, int* __restrict__ cnt, int E) {
  for (int e = blockIdx.x * blockDim.x + threadIdx.x; e < E;
       e += gridDim.x * blockDim.x)
    atomicAdd(&cnt[dsts[e]], 1);
}

__global__ __launch_bounds__(SCAN_T) void k_scan(int* __restrict__ cnt,
                                                 int* __restrict__ row_ptr) {
  __shared__ int part[SCAN_T];
  const int t = threadIdx.x;
  const int lo = t * SCAN_CH;
  const int hi = min(lo + SCAN_CH, NN);
  int s = 0;
  for (int i = lo; i < hi; ++i) s += cnt[i];
  part[t] = s;
  __syncthreads();
  for (int off = 1; off < SCAN_T; off <<= 1) {
    int v = (t >= off) ? part[t - off] : 0;
    __syncthreads();
    part[t] += v;
    __syncthreads();
  }
  int base = (t == 0) ? 0 : part[t - 1];
  for (int i = lo; i < hi; ++i) {
    const int c = cnt[i];
    row_ptr[i] = base;
    cnt[i] = base;
    base += c;
  }
  if (t == SCAN_T - 1) row_ptr[NN] = part[SCAN_T - 1];
}

__global__ void k_scatter(const int* __restrict__ srcs, const int* __restrict__ dsts,
                          int* __restrict__ cursor, int* __restrict__ csr, int E) {
  for (int e = blockIdx.x * blockDim.x + threadIdx.x; e < E;
       e += gridDim.x * blockDim.x) {
    const int pos = atomicAdd(&cursor[dsts[e]], 1);
    csr[pos] = srcs[e];
  }
}

__global__ __launch_bounds__(256) void k_aggregate_f32(const float* __restrict__ x,
    const float* __restrict__ epsp, const int* __restrict__ rowp,
    const int* __restrict__ csr, float* __restrict__ h0) {
  const int lane = threadIdx.x & 63;
  const int wid = blockIdx.x * 4 + (threadIdx.x >> 6);
  const int nw = gridDim.x * 4;
  const float ep = 1.0f + epsp[0];
  for (int v = wid; v < NN; v += nw) {
    const float2 xv = ((const float2*)(x + (size_t)v * D))[lane];
    float2 acc;
    acc.x = ep * xv.x;
    acc.y = ep * xv.y;
    const int beg = rowp[v], end = rowp[v + 1];
    for (int j = beg; j < end; ++j) {
      const float2 a = ((const float2*)(x + (size_t)csr[j] * D))[lane];
      acc.x += a.x;
      acc.y += a.y;
    }
    ((float2*)(h0 + (size_t)v * D))[lane] = acc;
  }
}

__global__ void k_init(const float* __restrict__ x, const float* __restrict__ epsp,
                       float* __restrict__ h0, float* __restrict__ stats) {
  if (blockIdx.x == 0 && threadIdx.x < 512) stats[threadIdx.x] = 0.0f;
  const float ep = 1.0f + epsp[0];
  const float4* x4 = (const float4*)x;
  float4* h4 = (float4*)h0;
  const int total = NN * D / 4;
  for (int i = blockIdx.x * blockDim.x + threadIdx.x; i < total;
       i += gridDim.x * blockDim.x) {
    float4 v = x4[i];
    v.x *= ep; v.y *= ep; v.z *= ep; v.w *= ep;
    h4[i] = v;
  }
}

__global__ void k_edges(const float* __restrict__ x, const int* __restrict__ srcs,
                        const int* __restrict__ dsts, float* __restrict__ h0, int E) {
  const int lane = threadIdx.x & 63;
  const int wave = blockIdx.x * (blockDim.x >> 6) + (threadIdx.x >> 6);
  const int e0 = wave * 8;
  const int e1 = min(e0 + 8, E);
  for (int e = e0; e < e1; ++e) {
    const int s = srcs[e];
    const int d = dsts[e];
    const float2 v = ((const float2*)(x + (size_t)s * D))[lane];
    float* p = h0 + (size_t)d * D + lane * 2;
    unsafeAtomicAdd(p, v.x);
    unsafeAtomicAdd(p + 1, v.y);
  }
}

__global__ __launch_bounds__(1024) void k_gemm1_vec(const float* h0, u16* h1,
    const float* __restrict__ W1, const float* __restrict__ b1,
    float* __restrict__ stats) {
  __shared__ float4 sW[D * D2 / 4];
  const float4* Wv = (const float4*)W1;
  for (int i = threadIdx.x; i < D * D2 / 4; i += 1024) sW[i] = Wv[i];
  __syncthreads();
  const int lane = threadIdx.x & 63;
  const int wv = blockIdx.x * 16 + (threadIdx.x >> 6);
  const int nwv = gridDim.x * 16;
  const float4 bias = ((const float4*)b1)[lane];
  float ssum[4] = {0.f, 0.f, 0.f, 0.f};
  float sqs[4]  = {0.f, 0.f, 0.f, 0.f};
  for (int rb = wv * 8; rb < NN; rb += nwv * 8) {
    float4 acc[8];
    #pragma unroll
    for (int r = 0; r < 8; ++r) acc[r] = bias;
    for (int k4 = 0; k4 < D / 4; ++k4) {
      const float4 w0 = sW[(k4 * 4 + 0) * (D2 / 4) + lane];
      const float4 w1 = sW[(k4 * 4 + 1) * (D2 / 4) + lane];
      const float4 w2 = sW[(k4 * 4 + 2) * (D2 / 4) + lane];
      const float4 w3 = sW[(k4 * 4 + 3) * (D2 / 4) + lane];
      #pragma unroll
      for (int r = 0; r < 8; ++r) {
        const float4 a = ((const float4*)(h0 + (size_t)(rb + r) * D))[k4];
        fma4(acc[r], a.x, w0);
        fma4(acc[r], a.y, w1);
        fma4(acc[r], a.z, w2);
        fma4(acc[r], a.w, w3);
      }
    }
    #pragma unroll
    for (int r = 0; r < 8; ++r) {
      ushort4 o;
      o.x = f2bf(acc[r].x); o.y = f2bf(acc[r].y);
      o.z = f2bf(acc[r].z); o.w = f2bf(acc[r].w);
      ((ushort4*)h1)[(size_t)(rb + r) * (D2 / 4) + lane] = o;
      ssum[0] += acc[r].x; ssum[1] += acc[r].y;
      ssum[2] += acc[r].z; ssum[3] += acc[r].w;
      sqs[0] += acc[r].x * acc[r].x; sqs[1] += acc[r].y * acc[r].y;
      sqs[2] += acc[r].z * acc[r].z; sqs[3] += acc[r].w * acc[r].w;
    }
  }
  __syncthreads();
  float* red = (float*)sW;
  const int w = threadIdx.x >> 6;
  #pragma unroll
  for (int c = 0; c < 4; ++c) {
    red[w * 512 + lane * 4 + c] = ssum[c];
    red[w * 512 + 256 + lane * 4 + c] = sqs[c];
  }
  __syncthreads();
  if (threadIdx.x < 512) {
    float s = 0.f;
    #pragma unroll
    for (int ww = 0; ww < 16; ++ww) s += red[ww * 512 + threadIdx.x];
    unsafeAtomicAdd(&stats[threadIdx.x], s);
  }
}

__global__ __launch_bounds__(1024) void k_gemm2_vec(const u16* h1, float* outp,
    const float* __restrict__ W2, const float* __restrict__ b2,
    const float* __restrict__ stats) {
  __shared__ float4 sW[D2 * D / 4];
  __shared__ float sS[D2], sT[D2];
  const float4* Wv = (const float4*)W2;
  for (int i = threadIdx.x; i < D2 * D / 4; i += 1024) sW[i] = Wv[i];
  if (threadIdx.x < D2) {
    sS[threadIdx.x] = stats[2 * D2 + threadIdx.x];
    sT[threadIdx.x] = stats[3 * D2 + threadIdx.x];
  }
  __syncthreads();
  const float2* sWf2 = (const float2*)sW;
  const int lane = threadIdx.x & 63;
  const int wv = blockIdx.x * 16 + (threadIdx.x >> 6);
  const int nwv = gridDim.x * 16;
  const float2 bias = ((const float2*)b2)[lane];
  for (int rb = wv * 8; rb < NN; rb += nwv * 8) {
    float2 acc[8];
    #pragma unroll
    for (int r = 0; r < 8; ++r) acc[r] = bias;
    for (int k4 = 0; k4 < D2 / 4; ++k4) {
      const float4 sv = ((const float4*)sS)[k4];
      const float4 tv = ((const float4*)sT)[k4];
      const float2 w0 = sWf2[(k4 * 4 + 0) * 64 + lane];
      const float2 w1 = sWf2[(k4 * 4 + 1) * 64 + lane];
      const float2 w2 = sWf2[(k4 * 4 + 2) * 64 + lane];
      const float2 w3 = sWf2[(k4 * 4 + 3) * 64 + lane];
      #pragma unroll
      for (int r = 0; r < 8; ++r) {
        const ushort4 a = ((const ushort4*)h1)[(size_t)(rb + r) * 64 + k4];
        const float ha = fmaxf(fmaf(bf2f(a.x), sv.x, tv.x), 0.f);
        const float hb = fmaxf(fmaf(bf2f(a.y), sv.y, tv.y), 0.f);
        const float hc = fmaxf(fmaf(bf2f(a.z), sv.z, tv.z), 0.f);
        const float hd = fmaxf(fmaf(bf2f(a.w), sv.w, tv.w), 0.f);
        acc[r].x = fmaf(ha, w0.x, acc[r].x); acc[r].y = fmaf(ha, w0.y, acc[r].y);
        acc[r].x = fmaf(hb, w1.x, acc[r].x); acc[r].y = fmaf(hb, w1.y, acc[r].y);
        acc[r].x = fmaf(hc, w2.x, acc[r].x); acc[r].y = fmaf(hc, w2.y, acc[r].y);
        acc[r].x = fmaf(hd, w3.x, acc[r].x); acc[r].y = fmaf(hd, w3.y, acc[r].y);
      }
    }
    #pragma unroll
    for (int r = 0; r < 8; ++r)
      ((float2*)outp)[(size_t)(rb + r) * 64 + lane] = acc[r];
  }
}

extern "C" void kernel_launch(void* const* d_in, const int* in_sizes, int n_in,
                              void* d_out, int out_size, void* d_ws, size_t ws_size,
                              hipStream_t stream) {
  const float* x     = (const float*)d_in[0];
  const int* ei      = (const int*)d_in[1];     // int32 (harness converts int64)
  const float* W1    = (const float*)d_in[2];
  const float* b1    = (const float*)d_in[3];
  const float* gamma = (const float*)d_in[4];
  const float* beta  = (const float*)d_in[5];
  const float* W2    = (const float*)d_in[6];
  const float* b2    = (const float*)d_in[7];
  const float* eps   = (const float*)d_in[8];
  const int E = in_sizes[1] / 2;

  float* out   = (float*)d_out;
  float* stats = (float*)d_ws;                  // [0,4K): sum|sumsq|s|t

  // binned-fast layout
  int* gh    = (int*)((char*)d_ws + 4096);      // 2048 ints
  int* gofs  = gh + 2048;                       // 2048 ints (needs NB+1)
  int* gcur  = gofs + 2048;                     // 2048 ints
  u32* pairs = (u32*)(gcur + 2048);             // E u32
  size_t offb = 4096 + 3 * 2048 * 4 + (size_t)E * 4;
  offb = (offb + 511) & ~(size_t)511;
  u16* h0bf = (u16*)((char*)d_ws + offb);       // NN*128 bf16
  u16* w1tr = h0bf + (size_t)NN * D;
  u16* w2tr = w1tr + D2 * D;
  const size_t need_bin = offb + 2u * ((size_t)NN * D + D2 * D + D * D2);

  // csr fallback layout
  int* cnt  = (int*)((char*)d_ws + 4096);
  int* rowp = cnt + NN;
  int* csr  = rowp + NN + 1;
  const size_t need_csr = 4096 + sizeof(int) * ((size_t)NN + (NN + 1) + E);

  if (ws_size >= need_bin) {
    hipMemsetAsync(d_ws, 0, 4096 + 2048 * 4, stream);        // stats + gh
    k_hist<<<256, 256, 0, stream>>>(ei + E, gh, E);
    k_binscan<<<1, 1024, 0, stream>>>(gh, gofs, gcur);
    k_bin<<<256, 256, 0, stream>>>(ei, ei + E, gcur, pairs, E);
    k_wprep<<<256, 256, 0, stream>>>(W1, W2, w1tr, w2tr);
    k_bagg<<<NB, 256, 0, stream>>>(x, eps, gofs, pairs, h0bf);
    k_gemm1_mfma<<<1563, 256, 0, stream>>>(h0bf, w1tr, b1, (u16*)out, stats);
    k_finalize<<<1, 256, 0, stream>>>(gamma, beta, stats);
    k_bnrelu<<<2048, 256, 0, stream>>>((u16*)out, stats);
    k_gemm2_mfma<<<782, 256, 0, stream>>>((const u16*)out, out, w2tr, b2);
  } else if (ws_size >= need_csr) {
    hipMemsetAsync(d_ws, 0, 4096 + (size_t)NN * 4, stream);
    k_count<<<2048, 256, 0, stream>>>(ei + E, cnt, E);
    k_scan<<<1, SCAN_T, 0, stream>>>(cnt, rowp);
    k_scatter<<<2048, 256, 0, stream>>>(ei, ei + E, cnt, csr, E);
    k_aggregate_f32<<<1600, 256, 0, stream>>>(x, eps, rowp, csr, out);
    k_gemm1_vec<<<256, 1024, 0, stream>>>(out, (u16*)out, W1, b1, stats);
    k_finalize<<<1, 256, 0, stream>>>(gamma, beta, stats);
    k_gemm2_vec<<<256, 1024, 0, stream>>>((const u16*)out, out, W2, b2, stats);
  } else {
    k_init<<<2048, 256, 0, stream>>>(x, eps, out, stats);
    k_edges<<<(E + 31) / 32, 256, 0, stream>>>(x, ei, ei + E, out, E);
    k_gemm1_vec<<<256, 1024, 0, stream>>>(out, (u16*)out, W1, b1, stats);
    k_finalize<<<1, 256, 0, stream>>>(gamma, beta, stats);
    k_gemm2_vec<<<256, 1024, 0, stream>>>((const u16*)out, out, W2, b2, stats);
  }
}

// Round 13
// 585.800 us; speedup vs baseline: 4.5571x; 4.5571x over previous
//
#include <hip/hip_runtime.h>

#define NN 100000
#define D 128
#define D2 256
#define NB 1563                     // ceil(NN/64) buckets of 64 nodes
#define SCAN_T 1024
#define SCAN_CH ((NN + SCAN_T - 1) / SCAN_T)   // 98

typedef unsigned short u16;
typedef unsigned int u32;
typedef __attribute__((ext_vector_type(8))) short short8v;
typedef __attribute__((ext_vector_type(8))) unsigned short ushort8v;
typedef __attribute__((ext_vector_type(16))) float f32x16;

__device__ __forceinline__ u16 f2bf(float f) {
  union { float f; u32 u; } v; v.f = f;
  u32 r = v.u + 0x7fffu + ((v.u >> 16) & 1u);   // round-nearest-even
  return (u16)(r >> 16);
}
__device__ __forceinline__ float bf2f(u16 u) {
  union { u32 u; float f; } v; v.u = ((u32)u) << 16;
  return v.f;
}
__device__ __forceinline__ void fma4(float4& acc, float a, const float4& w) {
  acc.x = fmaf(a, w.x, acc.x);
  acc.y = fmaf(a, w.y, acc.y);
  acc.z = fmaf(a, w.z, acc.z);
  acc.w = fmaf(a, w.w, acc.w);
}

// ---------- binned CSR build (no global scatter atomics) ----------
// B1: per-bucket histogram (LDS-aggregated)
__global__ __launch_bounds__(256) void k_hist(const int* __restrict__ dsts,
                                              int* __restrict__ gh, int E) {
  __shared__ int lh[NB];
  for (int i = threadIdx.x; i < NB; i += 256) lh[i] = 0;
  __syncthreads();
  for (int j = blockIdx.x * 256 + threadIdx.x; j < E; j += gridDim.x * 256)
    atomicAdd(&lh[dsts[j] >> 6], 1);
  __syncthreads();
  for (int i = threadIdx.x; i < NB; i += 256)
    if (lh[i]) atomicAdd(&gh[i], lh[i]);
}

// B2: exclusive scan over bucket counts -> gofs; init gcur
__global__ __launch_bounds__(1024) void k_binscan(const int* __restrict__ gh,
    int* __restrict__ gofs, int* __restrict__ gcur) {
  __shared__ int part[1024];
  const int t = threadIdx.x;
  const int i0 = 2 * t, i1 = 2 * t + 1;
  const int a = (i0 < NB) ? gh[i0] : 0;
  const int b = (i1 < NB) ? gh[i1] : 0;
  part[t] = a + b;
  __syncthreads();
  for (int off = 1; off < 1024; off <<= 1) {
    const int v = (t >= off) ? part[t - off] : 0;
    __syncthreads();
    part[t] += v;
    __syncthreads();
  }
  const int base = t ? part[t - 1] : 0;
  if (i0 < NB) { gofs[i0] = base; gcur[i0] = base; }
  if (i1 < NB) { gofs[i1] = base + a; gcur[i1] = base + a; }
  if (t == 0) gofs[NB] = part[1023];
}

// B3: bin edges into bucket-grouped pairs (src<<6 | dst&63); one global
// cursor atomic per (block,bucket), contiguous pair writes per run.
__global__ __launch_bounds__(256) void k_bin(const int* __restrict__ srcs,
    const int* __restrict__ dsts, int* __restrict__ gcur,
    u32* __restrict__ pairs, int E) {
  __shared__ int lh[NB], lbase[NB];
  const int chunk = (E + gridDim.x - 1) / gridDim.x;
  const int beg = blockIdx.x * chunk;
  const int end = min(beg + chunk, E);
  for (int i = threadIdx.x; i < NB; i += 256) lh[i] = 0;
  __syncthreads();
  for (int j = beg + threadIdx.x; j < end; j += 256)
    atomicAdd(&lh[dsts[j] >> 6], 1);
  __syncthreads();
  for (int i = threadIdx.x; i < NB; i += 256) {
    const int c = lh[i];
    lbase[i] = c ? atomicAdd(&gcur[i], c) : 0;
    lh[i] = 0;
  }
  __syncthreads();
  for (int j = beg + threadIdx.x; j < end; j += 256) {
    const int d = dsts[j];
    const int s = srcs[j];
    const int bb = d >> 6;
    const int loc = atomicAdd(&lh[bb], 1);
    pairs[lbase[bb] + loc] = ((u32)s << 6) | (u32)(d & 63);
  }
}

// B4: per-bucket LDS counting sort -> csr (src ids, CSR order) + rowp.
// All position atomics are LDS; csr writes stay within the bucket's window.
__global__ __launch_bounds__(256) void k_bsort(const u32* __restrict__ pairs,
    const int* __restrict__ gofs, int* __restrict__ csr, int* __restrict__ rowp,
    int E) {
  __shared__ int lcnt[64], lofs[64];
  const int b = blockIdx.x;
  const int beg = gofs[b], end = gofs[b + 1];
  if (threadIdx.x < 64) lcnt[threadIdx.x] = 0;
  __syncthreads();
  for (int j = beg + threadIdx.x; j < end; j += 256)
    atomicAdd(&lcnt[pairs[j] & 63], 1);
  __syncthreads();
  if (threadIdx.x == 0) {
    int acc = 0;
    #pragma unroll
    for (int i = 0; i < 64; ++i) { lofs[i] = acc; acc += lcnt[i]; }
  }
  __syncthreads();
  if (threadIdx.x < 64) {
    const int n = b * 64 + threadIdx.x;
    if (n < NN) rowp[n] = beg + lofs[threadIdx.x];
    lcnt[threadIdx.x] = lofs[threadIdx.x];     // reuse as cursor
  }
  if (b == NB - 1 && threadIdx.x == 0) rowp[NN] = E;
  __syncthreads();
  for (int j = beg + threadIdx.x; j < end; j += 256) {
    const u32 p = pairs[j];
    const int pos = atomicAdd(&lcnt[p & 63], 1);
    csr[beg + pos] = (int)(p >> 6);
  }
}

// ---------- fast path: aggregation + MFMA MLP (R11-proven) ----------
__global__ void k_wprep(const float* __restrict__ W1, const float* __restrict__ W2,
                        u16* __restrict__ w1tr, u16* __restrict__ w2tr) {
  const int t = blockIdx.x * blockDim.x + threadIdx.x;
  if (t < 32768) {
    const int n = t >> 7, k = t & 127;
    w1tr[t] = f2bf(W1[k * 256 + n]);
  } else if (t < 65536) {
    const int i = t - 32768;
    const int n = i >> 8, k = i & 255;
    w2tr[i] = f2bf(W2[k * 128 + n]);
  }
}

// one wave per node -> h0bf bf16 [NN][128]
__global__ __launch_bounds__(256) void k_aggregate_bf(const float* __restrict__ x,
    const float* __restrict__ epsp, const int* __restrict__ rowp,
    const int* __restrict__ csr, u16* __restrict__ h0bf) {
  const int lane = threadIdx.x & 63;
  const int wid = blockIdx.x * 4 + (threadIdx.x >> 6);
  const int nw = gridDim.x * 4;
  const float ep = 1.0f + epsp[0];
  for (int v = wid; v < NN; v += nw) {
    const float2 xv = ((const float2*)(x + (size_t)v * D))[lane];
    float2 acc;
    acc.x = ep * xv.x;
    acc.y = ep * xv.y;
    const int beg = rowp[v], end = rowp[v + 1];
    int j = beg;
    for (; j + 4 <= end; j += 4) {
      const int u0 = csr[j + 0], u1 = csr[j + 1];
      const int u2 = csr[j + 2], u3 = csr[j + 3];
      const float2 a0 = ((const float2*)(x + (size_t)u0 * D))[lane];
      const float2 a1 = ((const float2*)(x + (size_t)u1 * D))[lane];
      const float2 a2 = ((const float2*)(x + (size_t)u2 * D))[lane];
      const float2 a3 = ((const float2*)(x + (size_t)u3 * D))[lane];
      acc.x += a0.x + a1.x + a2.x + a3.x;
      acc.y += a0.y + a1.y + a2.y + a3.y;
    }
    for (; j < end; ++j) {
      const float2 a = ((const float2*)(x + (size_t)csr[j] * D))[lane];
      acc.x += a.x;
      acc.y += a.y;
    }
    const u32 pk = (u32)f2bf(acc.x) | ((u32)f2bf(acc.y) << 16);
    ((u32*)(h0bf + (size_t)v * D))[lane] = pk;
  }
}

// h1 = h0bf @ W1tr^T + b1 (32x32x16 bf16 MFMA) with fused BN stats
__global__ __launch_bounds__(256) void k_gemm1_mfma(const u16* __restrict__ h0bf,
    const u16* __restrict__ w1tr, const float* __restrict__ b1, u16* __restrict__ h1,
    float* __restrict__ stats) {
  __shared__ float ls[512];
  if (threadIdx.x < 256) { ls[threadIdx.x] = 0.0f; ls[threadIdx.x + 256] = 0.0f; }
  __syncthreads();
  const int lane = threadIdx.x & 63;
  const int l31 = lane & 31;
  const int khalf = (lane >> 5) * 8;
  const int gw = blockIdx.x * 4 + (threadIdx.x >> 6);
  const int nwv = gridDim.x * 4;
  for (int task = gw; task < (NN / 32) * 2; task += nwv) {
    const int chunk = task >> 1, cg = task & 1;
    const int arow = chunk * 32 + l31;
    f32x16 acc[4];
    #pragma unroll
    for (int i = 0; i < 4; ++i)
      #pragma unroll
      for (int j = 0; j < 16; ++j) acc[i][j] = 0.0f;
    const u16* ap = h0bf + (size_t)arow * 128 + khalf;
    const u16* bp = w1tr + ((size_t)(cg * 128 + l31)) * 128 + khalf;
    #pragma unroll
    for (int ks = 0; ks < 8; ++ks) {
      const short8v av = *(const short8v*)(ap + ks * 16);
      #pragma unroll
      for (int i = 0; i < 4; ++i) {
        const short8v bv = *(const short8v*)(bp + (size_t)i * 32 * 128 + ks * 16);
        acc[i] = __builtin_amdgcn_mfma_f32_32x32x16_bf16(av, bv, acc[i], 0, 0, 0);
      }
    }
    const int r0 = chunk * 32 + 4 * (lane >> 5);
    #pragma unroll
    for (int i = 0; i < 4; ++i) {
      const int col = cg * 128 + i * 32 + l31;
      const float bias = b1[col];
      float psum = 0.0f, psq = 0.0f;
      #pragma unroll
      for (int g = 0; g < 4; ++g)
        #pragma unroll
        for (int j = 0; j < 4; ++j) {
          const int row = r0 + 8 * g + j;
          const float h = acc[i][g * 4 + j] + bias;
          h1[(size_t)row * 256 + col] = f2bf(h);
          psum += h;
          psq += h * h;
        }
      unsafeAtomicAdd(&ls[col], psum);
      unsafeAtomicAdd(&ls[col + 256], psq);
    }
  }
  __syncthreads();
  if (threadIdx.x < 256) {
    unsafeAtomicAdd(&stats[threadIdx.x], ls[threadIdx.x]);
    unsafeAtomicAdd(&stats[threadIdx.x + 256], ls[threadIdx.x + 256]);
  }
}

__global__ void k_finalize(const float* __restrict__ gamma, const float* __restrict__ beta,
                           float* __restrict__ stats) {
  const int j = threadIdx.x;
  const float inv = 1.0f / (float)NN;
  const float mu = stats[j] * inv;
  const float var = fmaxf(stats[D2 + j] * inv - mu * mu, 0.0f);
  const float sc = gamma[j] * rsqrtf(var + 1e-5f);
  stats[2 * D2 + j] = sc;
  stats[3 * D2 + j] = beta[j] - mu * sc;
}

__global__ __launch_bounds__(256) void k_bnrelu(u16* h1, const float* __restrict__ stats) {
  const int tid = blockIdx.x * blockDim.x + threadIdx.x;
  const int c0 = (tid * 8) & 255;
  const float4 s0 = *(const float4*)(stats + 512 + c0);
  const float4 s1 = *(const float4*)(stats + 512 + c0 + 4);
  const float4 t0 = *(const float4*)(stats + 768 + c0);
  const float4 t1 = *(const float4*)(stats + 768 + c0 + 4);
  const float sv[8] = {s0.x, s0.y, s0.z, s0.w, s1.x, s1.y, s1.z, s1.w};
  const float tv[8] = {t0.x, t0.y, t0.z, t0.w, t1.x, t1.y, t1.z, t1.w};
  const int total = NN * D2 / 8;
  for (int i = tid; i < total; i += gridDim.x * blockDim.x) {
    ushort8v v = ((const ushort8v*)h1)[i];
    #pragma unroll
    for (int j = 0; j < 8; ++j)
      v[j] = f2bf(fmaxf(fmaf(bf2f(v[j]), sv[j], tv[j]), 0.0f));
    ((ushort8v*)h1)[i] = v;
  }
}

__global__ __launch_bounds__(256) void k_gemm2_mfma(const u16* h1, float* outp,
    const u16* __restrict__ w2tr, const float* __restrict__ b2) {
  const int lane = threadIdx.x & 63;
  const int l31 = lane & 31;
  const int khalf = (lane >> 5) * 8;
  const int gw = blockIdx.x * 4 + (threadIdx.x >> 6);
  const int nwv = gridDim.x * 4;
  for (int chunk = gw; chunk < NN / 32; chunk += nwv) {
    const int arow = chunk * 32 + l31;
    f32x16 acc[4];
    #pragma unroll
    for (int i = 0; i < 4; ++i)
      #pragma unroll
      for (int j = 0; j < 16; ++j) acc[i][j] = 0.0f;
    const u16* ap = h1 + (size_t)arow * 256 + khalf;
    const u16* bp = w2tr + (size_t)l31 * 256 + khalf;
    #pragma unroll
    for (int ks = 0; ks < 16; ++ks) {
      const short8v av = *(const short8v*)(ap + ks * 16);
      #pragma unroll
      for (int i = 0; i < 4; ++i) {
        const short8v bv = *(const short8v*)(bp + (size_t)i * 32 * 256 + ks * 16);
        acc[i] = __builtin_amdgcn_mfma_f32_32x32x16_bf16(av, bv, acc[i], 0, 0, 0);
      }
    }
    const int r0 = chunk * 32 + 4 * (lane >> 5);
    #pragma unroll
    for (int i = 0; i < 4; ++i) {
      const int col = i * 32 + l31;
      const float bias = b2[col];
      #pragma unroll
      for (int g = 0; g < 4; ++g)
        #pragma unroll
        for (int j = 0; j < 4; ++j) {
          const int row = r0 + 8 * g + j;
          outp[(size_t)row * 128 + col] = acc[i][g * 4 + j] + bias;
        }
    }
  }
}

// ---------- fallback tiers (proven R6/R8) ----------
__global__ void k_count(const int* __restrict__ dsts, int* __restrict__ cnt, int E) {
  for (int e = blockIdx.x * blockDim.x + threadIdx.x; e < E;
       e += gridDim.x * blockDim.x)
    atomicAdd(&cnt[dsts[e]], 1);
}

__global__ __launch_bounds__(SCAN_T) void k_scan(int* __restrict__ cnt,
                                                 int* __restrict__ row_ptr) {
  __shared__ int part[SCAN_T];
  const int t = threadIdx.x;
  const int lo = t * SCAN_CH;
  const int hi = min(lo + SCAN_CH, NN);
  int s = 0;
  for (int i = lo; i < hi; ++i) s += cnt[i];
  part[t] = s;
  __syncthreads();
  for (int off = 1; off < SCAN_T; off <<= 1) {
    int v = (t >= off) ? part[t - off] : 0;
    __syncthreads();
    part[t] += v;
    __syncthreads();
  }
  int base = (t == 0) ? 0 : part[t - 1];
  for (int i = lo; i < hi; ++i) {
    const int c = cnt[i];
    row_ptr[i] = base;
    cnt[i] = base;
    base += c;
  }
  if (t == SCAN_T - 1) row_ptr[NN] = part[SCAN_T - 1];
}

__global__ void k_scatter(const int* __restrict__ srcs, const int* __restrict__ dsts,
                          int* __restrict__ cursor, int* __restrict__ csr, int E) {
  for (int e = blockIdx.x * blockDim.x + threadIdx.x; e < E;
       e += gridDim.x * blockDim.x) {
    const int pos = atomicAdd(&cursor[dsts[e]], 1);
    csr[pos] = srcs[e];
  }
}

__global__ __launch_bounds__(256) void k_aggregate_f32(const float* __restrict__ x,
    const float* __restrict__ epsp, const int* __restrict__ rowp,
    const int* __restrict__ csr, float* __restrict__ h0) {
  const int lane = threadIdx.x & 63;
  const int wid = blockIdx.x * 4 + (threadIdx.x >> 6);
  const int nw = gridDim.x * 4;
  const float ep = 1.0f + epsp[0];
  for (int v = wid; v < NN; v += nw) {
    const float2 xv = ((const float2*)(x + (size_t)v * D))[lane];
    float2 acc;
    acc.x = ep * xv.x;
    acc.y = ep * xv.y;
    const int beg = rowp[v], end = rowp[v + 1];
    for (int j = beg; j < end; ++j) {
      const float2 a = ((const float2*)(x + (size_t)csr[j] * D))[lane];
      acc.x += a.x;
      acc.y += a.y;
    }
    ((float2*)(h0 + (size_t)v * D))[lane] = acc;
  }
}

__global__ void k_init(const float* __restrict__ x, const float* __restrict__ epsp,
                       float* __restrict__ h0, float* __restrict__ stats) {
  if (blockIdx.x == 0 && threadIdx.x < 512) stats[threadIdx.x] = 0.0f;
  const float ep = 1.0f + epsp[0];
  const float4* x4 = (const float4*)x;
  float4* h4 = (float4*)h0;
  const int total = NN * D / 4;
  for (int i = blockIdx.x * blockDim.x + threadIdx.x; i < total;
       i += gridDim.x * blockDim.x) {
    float4 v = x4[i];
    v.x *= ep; v.y *= ep; v.z *= ep; v.w *= ep;
    h4[i] = v;
  }
}

__global__ void k_edges(const float* __restrict__ x, const int* __restrict__ srcs,
                        const int* __restrict__ dsts, float* __restrict__ h0, int E) {
  const int lane = threadIdx.x & 63;
  const int wave = blockIdx.x * (blockDim.x >> 6) + (threadIdx.x >> 6);
  const int e0 = wave * 8;
  const int e1 = min(e0 + 8, E);
  for (int e = e0; e < e1; ++e) {
    const int s = srcs[e];
    const int d = dsts[e];
    const float2 v = ((const float2*)(x + (size_t)s * D))[lane];
    float* p = h0 + (size_t)d * D + lane * 2;
    unsafeAtomicAdd(p, v.x);
    unsafeAtomicAdd(p + 1, v.y);
  }
}

__global__ __launch_bounds__(1024) void k_gemm1_vec(const float* h0, u16* h1,
    const float* __restrict__ W1, const float* __restrict__ b1,
    float* __restrict__ stats) {
  __shared__ float4 sW[D * D2 / 4];
  const float4* Wv = (const float4*)W1;
  for (int i = threadIdx.x; i < D * D2 / 4; i += 1024) sW[i] = Wv[i];
  __syncthreads();
  const int lane = threadIdx.x & 63;
  const int wv = blockIdx.x * 16 + (threadIdx.x >> 6);
  const int nwv = gridDim.x * 16;
  const float4 bias = ((const float4*)b1)[lane];
  float ssum[4] = {0.f, 0.f, 0.f, 0.f};
  float sqs[4]  = {0.f, 0.f, 0.f, 0.f};
  for (int rb = wv * 8; rb < NN; rb += nwv * 8) {
    float4 acc[8];
    #pragma unroll
    for (int r = 0; r < 8; ++r) acc[r] = bias;
    for (int k4 = 0; k4 < D / 4; ++k4) {
      const float4 w0 = sW[(k4 * 4 + 0) * (D2 / 4) + lane];
      const float4 w1 = sW[(k4 * 4 + 1) * (D2 / 4) + lane];
      const float4 w2 = sW[(k4 * 4 + 2) * (D2 / 4) + lane];
      const float4 w3 = sW[(k4 * 4 + 3) * (D2 / 4) + lane];
      #pragma unroll
      for (int r = 0; r < 8; ++r) {
        const float4 a = ((const float4*)(h0 + (size_t)(rb + r) * D))[k4];
        fma4(acc[r], a.x, w0);
        fma4(acc[r], a.y, w1);
        fma4(acc[r], a.z, w2);
        fma4(acc[r], a.w, w3);
      }
    }
    #pragma unroll
    for (int r = 0; r < 8; ++r) {
      ushort4 o;
      o.x = f2bf(acc[r].x); o.y = f2bf(acc[r].y);
      o.z = f2bf(acc[r].z); o.w = f2bf(acc[r].w);
      ((ushort4*)h1)[(size_t)(rb + r) * (D2 / 4) + lane] = o;
      ssum[0] += acc[r].x; ssum[1] += acc[r].y;
      ssum[2] += acc[r].z; ssum[3] += acc[r].w;
      sqs[0] += acc[r].x * acc[r].x; sqs[1] += acc[r].y * acc[r].y;
      sqs[2] += acc[r].z * acc[r].z; sqs[3] += acc[r].w * acc[r].w;
    }
  }
  __syncthreads();
  float* red = (float*)sW;
  const int w = threadIdx.x >> 6;
  #pragma unroll
  for (int c = 0; c < 4; ++c) {
    red[w * 512 + lane * 4 + c] = ssum[c];
    red[w * 512 + 256 + lane * 4 + c] = sqs[c];
  }
  __syncthreads();
  if (threadIdx.x < 512) {
    float s = 0.f;
    #pragma unroll
    for (int ww = 0; ww < 16; ++ww) s += red[ww * 512 + threadIdx.x];
    unsafeAtomicAdd(&stats[threadIdx.x], s);
  }
}

__global__ __launch_bounds__(1024) void k_gemm2_vec(const u16* h1, float* outp,
    const float* __restrict__ W2, const float* __restrict__ b2,
    const float* __restrict__ stats) {
  __shared__ float4 sW[D2 * D / 4];
  __shared__ float sS[D2], sT[D2];
  const float4* Wv = (const float4*)W2;
  for (int i = threadIdx.x; i < D2 * D / 4; i += 1024) sW[i] = Wv[i];
  if (threadIdx.x < D2) {
    sS[threadIdx.x] = stats[2 * D2 + threadIdx.x];
    sT[threadIdx.x] = stats[3 * D2 + threadIdx.x];
  }
  __syncthreads();
  const float2* sWf2 = (const float2*)sW;
  const int lane = threadIdx.x & 63;
  const int wv = blockIdx.x * 16 + (threadIdx.x >> 6);
  const int nwv = gridDim.x * 16;
  const float2 bias = ((const float2*)b2)[lane];
  for (int rb = wv * 8; rb < NN; rb += nwv * 8) {
    float2 acc[8];
    #pragma unroll
    for (int r = 0; r < 8; ++r) acc[r] = bias;
    for (int k4 = 0; k4 < D2 / 4; ++k4) {
      const float4 sv = ((const float4*)sS)[k4];
      const float4 tv = ((const float4*)sT)[k4];
      const float2 w0 = sWf2[(k4 * 4 + 0) * 64 + lane];
      const float2 w1 = sWf2[(k4 * 4 + 1) * 64 + lane];
      const float2 w2 = sWf2[(k4 * 4 + 2) * 64 + lane];
      const float2 w3 = sWf2[(k4 * 4 + 3) * 64 + lane];
      #pragma unroll
      for (int r = 0; r < 8; ++r) {
        const ushort4 a = ((const ushort4*)h1)[(size_t)(rb + r) * 64 + k4];
        const float ha = fmaxf(fmaf(bf2f(a.x), sv.x, tv.x), 0.f);
        const float hb = fmaxf(fmaf(bf2f(a.y), sv.y, tv.y), 0.f);
        const float hc = fmaxf(fmaf(bf2f(a.z), sv.z, tv.z), 0.f);
        const float hd = fmaxf(fmaf(bf2f(a.w), sv.w, tv.w), 0.f);
        acc[r].x = fmaf(ha, w0.x, acc[r].x); acc[r].y = fmaf(ha, w0.y, acc[r].y);
        acc[r].x = fmaf(hb, w1.x, acc[r].x); acc[r].y = fmaf(hb, w1.y, acc[r].y);
        acc[r].x = fmaf(hc, w2.x, acc[r].x); acc[r].y = fmaf(hc, w2.y, acc[r].y);
        acc[r].x = fmaf(hd, w3.x, acc[r].x); acc[r].y = fmaf(hd, w3.y, acc[r].y);
      }
    }
    #pragma unroll
    for (int r = 0; r < 8; ++r)
      ((float2*)outp)[(size_t)(rb + r) * 64 + lane] = acc[r];
  }
}

extern "C" void kernel_launch(void* const* d_in, const int* in_sizes, int n_in,
                              void* d_out, int out_size, void* d_ws, size_t ws_size,
                              hipStream_t stream) {
  const float* x     = (const float*)d_in[0];
  const int* ei      = (const int*)d_in[1];     // int32 (harness converts int64)
  const float* W1    = (const float*)d_in[2];
  const float* b1    = (const float*)d_in[3];
  const float* gamma = (const float*)d_in[4];
  const float* beta  = (const float*)d_in[5];
  const float* W2    = (const float*)d_in[6];
  const float* b2    = (const float*)d_in[7];
  const float* eps   = (const float*)d_in[8];
  const int E = in_sizes[1] / 2;

  float* out   = (float*)d_out;
  float* stats = (float*)d_ws;                  // [0,4K): sum|sumsq|s|t

  // binned-fast layout (total ≈ 38.96 MB, fits the proven-available 39.29 MB)
  int* gh    = (int*)((char*)d_ws + 4096);      // 2048 ints
  int* gofs  = gh + 2048;                       // 2048 ints (NB+1 used)
  int* gcur  = gofs + 2048;                     // 2048 ints
  int* csr   = gcur + 2048;                     // E ints
  int* rowp  = csr + E;                         // NN+1 ints
  size_t woff = 4096 + 4u * (3 * 2048 + (size_t)E + NN + 1);
  woff = (woff + 511) & ~(size_t)511;
  u16* w1tr = (u16*)((char*)d_ws + woff);       // 256*128 bf16
  u16* w2tr = w1tr + D2 * D;                    // 128*256 bf16
  size_t hoff = woff + 2u * (D2 * D + D * D2);
  hoff = (hoff + 511) & ~(size_t)511;
  u16* h0bf = (u16*)((char*)d_ws + hoff);       // NN*128 bf16 = 25.6 MB
  // pairs aliases the TAIL HALF of h0bf: dead before h0bf is written
  u32* pairs = (u32*)((char*)h0bf + (size_t)NN * D);  // E u32 = 12.8 MB
  const size_t need_bin = hoff + 2u * (size_t)NN * D;

  // csr fallback layout
  int* cnt   = (int*)((char*)d_ws + 4096);
  int* rowp2 = cnt + NN;
  int* csr2  = rowp2 + NN + 1;
  const size_t need_csr = 4096 + sizeof(int) * ((size_t)NN + (NN + 1) + E);

  if (ws_size >= need_bin) {
    hipMemsetAsync(d_ws, 0, 4096 + 2048 * 4, stream);        // stats + gh
    k_hist<<<256, 256, 0, stream>>>(ei + E, gh, E);
    k_binscan<<<1, 1024, 0, stream>>>(gh, gofs, gcur);
    k_bin<<<256, 256, 0, stream>>>(ei, ei + E, gcur, pairs, E);
    k_bsort<<<NB, 256, 0, stream>>>(pairs, gofs, csr, rowp, E);
    k_wprep<<<256, 256, 0, stream>>>(W1, W2, w1tr, w2tr);
    k_aggregate_bf<<<1600, 256, 0, stream>>>(x, eps, rowp, csr, h0bf);
    k_gemm1_mfma<<<1563, 256, 0, stream>>>(h0bf, w1tr, b1, (u16*)out, stats);
    k_finalize<<<1, 256, 0, stream>>>(gamma, beta, stats);
    k_bnrelu<<<2048, 256, 0, stream>>>((u16*)out, stats);
    k_gemm2_mfma<<<782, 256, 0, stream>>>((const u16*)out, out, w2tr, b2);
  } else if (ws_size >= need_csr) {
    hipMemsetAsync(d_ws, 0, 4096 + (size_t)NN * 4, stream);
    k_count<<<2048, 256, 0, stream>>>(ei + E, cnt, E);
    k_scan<<<1, SCAN_T, 0, stream>>>(cnt, rowp2);
    k_scatter<<<2048, 256, 0, stream>>>(ei, ei + E, cnt, csr2, E);
    k_aggregate_f32<<<1600, 256, 0, stream>>>(x, eps, rowp2, csr2, out);
    k_gemm1_vec<<<256, 1024, 0, stream>>>(out, (u16*)out, W1, b1, stats);
    k_finalize<<<1, 256, 0, stream>>>(gamma, beta, stats);
    k_gemm2_vec<<<256, 1024, 0, stream>>>((const u16*)out, out, W2, b2, stats);
  } else {
    k_init<<<2048, 256, 0, stream>>>(x, eps, out, stats);
    k_edges<<<(E + 31) / 32, 256, 0, stream>>>(x, ei, ei + E, out, E);
    k_gemm1_vec<<<256, 1024, 0, stream>>>(out, (u16*)out, W1, b1, stats);
    k_finalize<<<1, 256, 0, stream>>>(gamma, beta, stats);
    k_gemm2_vec<<<256, 1024, 0, stream>>>((const u16*)out, out, W2, b2, stats);
  }
}